// Round 2
// baseline (406.771 us; speedup 1.0000x reference)
//
#include <hip/hip_runtime.h>
#include <math.h>

#define BATCH 128
#define NINS  4096
#define NHID  128
#define KH    64
#define NPART 128                   // 128 tiles of 32 n per batch
#define PART_STRIDE 136             // [0]=L, [8..135]=o[128]; 16B-aligned
#define O_OFF 8
#define TPW 2                       // tiles per wave
#define XP 136                      // WbT row pitch in ushort (128 bf16 + 8 pad)

typedef __attribute__((ext_vector_type(8))) short short8;   // 8 x bf16
typedef __attribute__((ext_vector_type(4))) float f32x4;
typedef __attribute__((ext_vector_type(4))) unsigned int u32x4;

__device__ inline unsigned short f2bf(float f) {
    union { float f; unsigned u; } v; v.f = f;
    return (unsigned short)((v.u + 0x7FFFu + ((v.u >> 16) & 1u)) >> 16);
}

// packed fp32x2 -> bf16x2 as u32 (hardware v_cvt_pk_bf16_f32 on gfx950)
__device__ inline unsigned cvt_pk_u32(float a, float b) {
#if __has_builtin(__builtin_amdgcn_cvt_pk_bf16_f32)
    typedef __attribute__((ext_vector_type(2))) __bf16 bf16x2;
    bf16x2 p = __builtin_amdgcn_cvt_pk_bf16_f32(a, b);
    unsigned u; __builtin_memcpy(&u, &p, 4); return u;
#else
    return (unsigned)f2bf(a) | ((unsigned)f2bf(b) << 16);
#endif
}

// --------------------------------------------------------------------------
// Kernel A: c[b][k] = b1[k] + sum_d inputs[b,index,d] * W1[d][k]  (fp32 exact)
// --------------------------------------------------------------------------
__global__ void precompute_c(const float* __restrict__ inputs,
                             const int* __restrict__ index_p,
                             const float* __restrict__ W1,
                             const float* __restrict__ b1,
                             float* __restrict__ c) {
    const int b = blockIdx.x;
    const int k = threadIdx.x;   // 0..63
    const int idx = index_p[0];
    const float* own = inputs + ((size_t)b * NINS + idx) * NHID;
    float acc = b1[k];
    #pragma unroll 8
    for (int d = 0; d < NHID; ++d)
        acc = fmaf(own[d], W1[d * KH + k], acc);
    c[b * KH + k] = acc;
}

// --------------------------------------------------------------------------
// Kernel B: MFMA main pass, direct global->register A-fragments,
// software-pipelined across tiles: tile t+1's fp32 frag loads are ISSUED
// right after tile t's accumulator is consumed (registers free), and
// converted to bf16 after the exp/L phase — the HBM miss hides under
// ~400+ cycles of epilogue + weighted-sum.  No per-tile max subtraction:
// att is bounded (|att| < ~10 for N(0,1) inputs with 1/sqrt(fanin) W),
// exp(att) is safe in fp32 and softmax is algebraically identical, so the
// partial is just (L, o[128]) and finalize becomes a pure sum.
// --------------------------------------------------------------------------
__global__ __launch_bounds__(256, 4)
void att_partial(const float* __restrict__ inputs,
                 const float* __restrict__ W1,
                 const float* __restrict__ W2,
                 const float* __restrict__ b2_p,
                 const float* __restrict__ c,
                 float* __restrict__ part) {
    __shared__ unsigned short WbT[KH][XP];       // [out k][hidden d] bf16, 17.4 KB
    __shared__ float ebuf[4][32];

    const int tid  = threadIdx.x;
    const int lane = tid & 63;
    const int wv   = tid >> 6;
    const int b    = blockIdx.y;
    const int quad = lane >> 4;
    const int m16  = lane & 15;

    const float* xb = inputs + (size_t)b * NINS * NHID;

    // ---- stage WbT[k][d] = bf16(W1[128+d][k]) (whole block, once) ----
    {
        const int n  = tid >> 2;            // 0..63 (output k)
        const int kb = (tid & 3) * 32;      // 0,32,64,96 (hidden d base)
        const float* wp = W1 + (size_t)(NHID + kb) * KH + n;
        #pragma unroll
        for (int j = 0; j < 32; j += 2) {
            unsigned u = cvt_pk_u32(wp[(size_t)j * KH], wp[(size_t)(j + 1) * KH]);
            *(unsigned*)&WbT[n][kb + j] = u;
        }
    }
    __syncthreads();

    float w2v[4];
    #pragma unroll
    for (int nf = 0; nf < 4; ++nf) w2v[nf] = W2[nf * 16 + m16];
    const float b2v = b2_p[0];
    float cv[4];
    #pragma unroll
    for (int nf = 0; nf < 4; ++nf) cv[nf] = c[b * KH + nf * 16 + m16];

    const int base = (blockIdx.x * 4 + wv) * TPW;   // first tile of this wave

    f32x4 raw[2][4][2];     // next-tile fp32 frag data (transient, 64 VGPR)
    short8 Af[2][4];        // current-tile bf16 A-frags

    auto load_raw = [&](int n0) {
        #pragma unroll
        for (int mf = 0; mf < 2; ++mf) {
            const float* rp = xb + (size_t)(n0 + mf * 16 + m16) * NHID + quad * 8;
            #pragma unroll
            for (int ks = 0; ks < 4; ++ks) {
                raw[mf][ks][0] = *(const f32x4*)(rp + ks * 32);
                raw[mf][ks][1] = *(const f32x4*)(rp + ks * 32 + 4);
            }
        }
    };
    auto cvt_raw = [&]() {
        #pragma unroll
        for (int mf = 0; mf < 2; ++mf)
            #pragma unroll
            for (int ks = 0; ks < 4; ++ks) {
                u32x4 u;
                u.x = cvt_pk_u32(raw[mf][ks][0].x, raw[mf][ks][0].y);
                u.y = cvt_pk_u32(raw[mf][ks][0].z, raw[mf][ks][0].w);
                u.z = cvt_pk_u32(raw[mf][ks][1].x, raw[mf][ks][1].y);
                u.w = cvt_pk_u32(raw[mf][ks][1].z, raw[mf][ks][1].w);
                __builtin_memcpy(&Af[mf][ks], &u, 16);
            }
    };

    // prologue: tile 0 frags
    load_raw(base * 32);
    cvt_raw();

    #pragma unroll
    for (int t = 0; t < TPW; ++t) {
        const int tile = base + t;
        const int n0   = tile * 32;

        f32x4 acc[2][4];
        #pragma unroll
        for (int mf = 0; mf < 2; ++mf)
            #pragma unroll
            for (int nf = 0; nf < 4; ++nf) {
                f32x4 z = {cv[nf], cv[nf], cv[nf], cv[nf]};
                acc[mf][nf] = z;
            }

        #pragma unroll
        for (int ks = 0; ks < 4; ++ks) {
            short8 Bf[4];
            #pragma unroll
            for (int nf = 0; nf < 4; ++nf)
                Bf[nf] = *(const short8*)&WbT[nf * 16 + m16][ks * 32 + quad * 8];
            #pragma unroll
            for (int mf = 0; mf < 2; ++mf)
                #pragma unroll
                for (int nf = 0; nf < 4; ++nf)
                    acc[mf][nf] = __builtin_amdgcn_mfma_f32_16x16x32_bf16(
                        Af[mf][ks], Bf[nf], acc[mf][nf], 0, 0, 0);
        }

        // ---- epilogue: att[n] = b2 + sum_k relu(h[n][k]) * W2[k] ----
        // C layout: row(n-in-tile) = mf*16 + quad*4 + r, col(hidden k) = nf*16+m16
        float att[2][4];
        #pragma unroll
        for (int mf = 0; mf < 2; ++mf)
            #pragma unroll
            for (int r = 0; r < 4; ++r) {
                float s = 0.0f;
                #pragma unroll
                for (int nf = 0; nf < 4; ++nf)
                    s = fmaf(fmaxf(acc[mf][nf][r], 0.0f), w2v[nf], s);
                s += __shfl_xor(s, 1);
                s += __shfl_xor(s, 2);
                s += __shfl_xor(s, 4);
                s += __shfl_xor(s, 8);
                att[mf][r] = s + b2v;
            }

        // ---- PREFETCH: issue next tile's frag loads (acc is dead now) ----
        if (t + 1 < TPW) load_raw((tile + 1) * 32);

        // ---- exp (no max subtraction) + L reduce ----
        float ev[2][4];
        float L = 0.0f;
        #pragma unroll
        for (int mf = 0; mf < 2; ++mf)
            #pragma unroll
            for (int r = 0; r < 4; ++r) {
                ev[mf][r] = __expf(att[mf][r]);
                L += ev[mf][r];
            }
        L += __shfl_xor(L, 16);
        L += __shfl_xor(L, 32);

        if (m16 == 0) {
            #pragma unroll
            for (int mf = 0; mf < 2; ++mf)
                #pragma unroll
                for (int r = 0; r < 4; ++r)
                    ebuf[wv][mf * 16 + quad * 4 + r] = ev[mf][r];
        }
        // same-wave DS ordering; compiler inserts lgkmcnt wait before reads

        // ---- convert prefetched frags (HBM latency now mostly covered) ----
        if (t + 1 < TPW) cvt_raw();

        // ---- weighted sum: o[d] = sum_n e_n * x[n][d]  (x fp32, L2-hot) ----
        const int G  = lane >> 5;            // n-half (16 each)
        const int db = (lane & 31) * 4;      // d-base (float4)
        f32x4 e4[4];
        #pragma unroll
        for (int i = 0; i < 4; ++i)
            e4[i] = *(const f32x4*)&ebuf[wv][G * 16 + i * 4];

        f32x4 o = {0.0f, 0.0f, 0.0f, 0.0f};
        const float* xr = xb + (size_t)(n0 + G * 16) * NHID + db;
        #pragma unroll
        for (int jj = 0; jj < 16; ++jj) {
            f32x4 xv = *(const f32x4*)(xr + (size_t)jj * NHID);
            o += xv * e4[jj >> 2][jj & 3];
        }
        #pragma unroll
        for (int i = 0; i < 4; ++i) o[i] += __shfl_xor(o[i], 32);

        float* p = part + (size_t)(b * NPART + tile) * PART_STRIDE;
        if (lane == 0) p[0] = L;
        if (lane < 32) *(f32x4*)(p + O_OFF + db) = o;
    }
}

// --------------------------------------------------------------------------
// Kernel C: merge 128 partials per batch -> out[b][d]
// No max pass: S = sum of L_p (block reduce), then a coalesced plain sum
// over partials. No exp, single __syncthreads.
// --------------------------------------------------------------------------
__global__ void finalize(const float* __restrict__ part,
                         float* __restrict__ out) {
    __shared__ float wred[2];

    const int b = blockIdx.x;
    const int d = threadIdx.x;     // 0..127 (= partial index in phase 1)
    const float* pb = part + (size_t)b * NPART * PART_STRIDE;

    // phase 1: S = sum of per-partial L
    float s = pb[(size_t)d * PART_STRIDE];
    s += __shfl_xor(s, 1);
    s += __shfl_xor(s, 2);
    s += __shfl_xor(s, 4);
    s += __shfl_xor(s, 8);
    s += __shfl_xor(s, 16);
    s += __shfl_xor(s, 32);
    if ((d & 63) == 0) wred[d >> 6] = s;
    __syncthreads();
    const float S = wred[0] + wred[1];

    // phase 2: acc over partials, d is the hidden index (coalesced)
    float acc = 0.0f;
    #pragma unroll 8
    for (int p = 0; p < NPART; ++p)
        acc += pb[(size_t)p * PART_STRIDE + O_OFF + d];
    out[b * NHID + d] = acc / S;
}

// --------------------------------------------------------------------------
extern "C" void kernel_launch(void* const* d_in, const int* in_sizes, int n_in,
                              void* d_out, int out_size, void* d_ws, size_t ws_size,
                              hipStream_t stream) {
    const float* inputs = (const float*)d_in[0];
    const int*   index  = (const int*)  d_in[1];
    // d_in[2] = claims (unused by forward)
    const float* W1     = (const float*)d_in[3];
    const float* b1     = (const float*)d_in[4];
    const float* W2     = (const float*)d_in[5];
    const float* b2     = (const float*)d_in[6];
    float* out = (float*)d_out;

    float* c    = (float*)d_ws;                 // 128*64 floats = 32 KB
    float* part = c + BATCH * KH;               // 128*128*136 floats ~= 8.9 MB

    precompute_c<<<dim3(BATCH), dim3(64), 0, stream>>>(inputs, index, W1, b1, c);

    dim3 gB(NPART / (4 * TPW), BATCH);          // 16 x 128 = 2048 blocks, 4 waves
    att_partial<<<gB, dim3(256), 0, stream>>>(inputs, W1, W2, b2, c, part);

    finalize<<<dim3(BATCH), dim3(NHID), 0, stream>>>(part, out);
}

// Round 3
// 386.812 us; speedup vs baseline: 1.0516x; 1.0516x over previous
//
#include <hip/hip_runtime.h>
#include <math.h>

#define BATCH 128
#define NINS  4096
#define NHID  128
#define KH    64
#define NPART 128                   // 128 tiles of 32 n per batch
#define PART_STRIDE 136             // [0]=L, [8..135]=o[128]; 16B-aligned
#define O_OFF 8
#define TPW 2                       // tiles per wave
#define XP 136                      // WbT row pitch in ushort (128 bf16 + 8 pad)

typedef __attribute__((ext_vector_type(8))) short short8;   // 8 x bf16
typedef __attribute__((ext_vector_type(4))) float f32x4;
typedef __attribute__((ext_vector_type(4))) unsigned int u32x4;

__device__ inline unsigned short f2bf(float f) {
    union { float f; unsigned u; } v; v.f = f;
    return (unsigned short)((v.u + 0x7FFFu + ((v.u >> 16) & 1u)) >> 16);
}

// packed fp32x2 -> bf16x2 as u32 (hardware v_cvt_pk_bf16_f32 on gfx950)
__device__ inline unsigned cvt_pk_u32(float a, float b) {
#if __has_builtin(__builtin_amdgcn_cvt_pk_bf16_f32)
    typedef __attribute__((ext_vector_type(2))) __bf16 bf16x2;
    bf16x2 p = __builtin_amdgcn_cvt_pk_bf16_f32(a, b);
    unsigned u; __builtin_memcpy(&u, &p, 4); return u;
#else
    return (unsigned)f2bf(a) | ((unsigned)f2bf(b) << 16);
#endif
}

// --------------------------------------------------------------------------
// Kernel B: MFMA main pass, direct global->register A-fragments (compiler-
// scheduled loads — R2 showed explicit raw[]/cvt pipelining regresses via
// register pressure). Fused c-compute: each block redundantly computes
// c[b][k] = b1[k] + own . W1[0:128][k] during the WbT staging phase
// (4-way d-split across waves into LDS), killing the separate kernel and
// the c global round-trip. No per-tile max subtraction: att is bounded
// (|att| < ~10 for N(0,1) inputs, 1/sqrt(fanin) W), exp is fp32-safe and
// softmax is algebraically identical, so the partial is (L, o[128]) and
// finalize is a pure sum.
// --------------------------------------------------------------------------
__global__ __launch_bounds__(256, 4)
void att_partial(const float* __restrict__ inputs,
                 const int* __restrict__ index_p,
                 const float* __restrict__ W1,
                 const float* __restrict__ b1,
                 const float* __restrict__ W2,
                 const float* __restrict__ b2_p,
                 float* __restrict__ part) {
    __shared__ unsigned short WbT[KH][XP];       // [out k][hidden d] bf16, 17.4 KB
    __shared__ float csp[4][KH];                 // c partial sums (d-quarters)
    __shared__ float ebuf[4][32];

    const int tid  = threadIdx.x;
    const int lane = tid & 63;
    const int wv   = tid >> 6;
    const int b    = blockIdx.y;
    const int quad = lane >> 4;
    const int m16  = lane & 15;

    const float* xb = inputs + (size_t)b * NINS * NHID;

    // ---- stage WbT[k][d] = bf16(W1[128+d][k]) (whole block, once) ----
    {
        const int n  = tid >> 2;            // 0..63 (output k)
        const int kb = (tid & 3) * 32;      // 0,32,64,96 (hidden d base)
        const float* wp = W1 + (size_t)(NHID + kb) * KH + n;
        #pragma unroll
        for (int j = 0; j < 32; j += 2) {
            unsigned u = cvt_pk_u32(wp[(size_t)j * KH], wp[(size_t)(j + 1) * KH]);
            *(unsigned*)&WbT[n][kb + j] = u;
        }
    }

    // ---- fused c-compute: csp[q][k] = partial_d own[d]*W1[d][k] ----
    {
        const int kk = lane;                 // 0..63
        const int dq = wv;                   // d-quarter
        const int idx = index_p[0];
        const float* own = xb + (size_t)idx * NHID;
        float ca = (dq == 0) ? b1[kk] : 0.0f;
        #pragma unroll 8
        for (int d = dq * 32; d < dq * 32 + 32; ++d)
            ca = fmaf(own[d], W1[(size_t)d * KH + kk], ca);
        csp[dq][kk] = ca;
    }
    __syncthreads();

    float w2v[4];
    #pragma unroll
    for (int nf = 0; nf < 4; ++nf) w2v[nf] = W2[nf * 16 + m16];
    const float b2v = b2_p[0];
    float cv[4];
    #pragma unroll
    for (int nf = 0; nf < 4; ++nf) {
        const int kk = nf * 16 + m16;
        cv[nf] = (csp[0][kk] + csp[1][kk]) + (csp[2][kk] + csp[3][kk]);
    }

    const int base = (blockIdx.x * 4 + wv) * TPW;   // first tile of this wave

    #pragma unroll
    for (int t = 0; t < TPW; ++t) {
        const int tile = base + t;
        const int n0   = tile * 32;

        // ---- A-frags: global fp32 -> bf16 regs (no LDS round trip) ----
        short8 Af[2][4];    // [mf][ks]
        #pragma unroll
        for (int mf = 0; mf < 2; ++mf) {
            const float* rp = xb + (size_t)(n0 + mf * 16 + m16) * NHID + quad * 8;
            #pragma unroll
            for (int ks = 0; ks < 4; ++ks) {
                f32x4 v0 = *(const f32x4*)(rp + ks * 32);
                f32x4 v1 = *(const f32x4*)(rp + ks * 32 + 4);
                u32x4 u;
                u.x = cvt_pk_u32(v0.x, v0.y);
                u.y = cvt_pk_u32(v0.z, v0.w);
                u.z = cvt_pk_u32(v1.x, v1.y);
                u.w = cvt_pk_u32(v1.z, v1.w);
                __builtin_memcpy(&Af[mf][ks], &u, 16);
            }
        }

        f32x4 acc[2][4];
        #pragma unroll
        for (int mf = 0; mf < 2; ++mf)
            #pragma unroll
            for (int nf = 0; nf < 4; ++nf) {
                f32x4 z = {cv[nf], cv[nf], cv[nf], cv[nf]};
                acc[mf][nf] = z;
            }

        #pragma unroll
        for (int ks = 0; ks < 4; ++ks) {
            short8 Bf[4];
            #pragma unroll
            for (int nf = 0; nf < 4; ++nf)
                Bf[nf] = *(const short8*)&WbT[nf * 16 + m16][ks * 32 + quad * 8];
            #pragma unroll
            for (int mf = 0; mf < 2; ++mf)
                #pragma unroll
                for (int nf = 0; nf < 4; ++nf)
                    acc[mf][nf] = __builtin_amdgcn_mfma_f32_16x16x32_bf16(
                        Af[mf][ks], Bf[nf], acc[mf][nf], 0, 0, 0);
        }

        // ---- epilogue: att[n] = b2 + sum_k relu(h[n][k]) * W2[k] ----
        // C layout: row(n-in-tile) = mf*16 + quad*4 + r, col(hidden k) = nf*16+m16
        float att[2][4];
        #pragma unroll
        for (int mf = 0; mf < 2; ++mf)
            #pragma unroll
            for (int r = 0; r < 4; ++r) {
                float s = 0.0f;
                #pragma unroll
                for (int nf = 0; nf < 4; ++nf)
                    s = fmaf(fmaxf(acc[mf][nf][r], 0.0f), w2v[nf], s);
                s += __shfl_xor(s, 1);
                s += __shfl_xor(s, 2);
                s += __shfl_xor(s, 4);
                s += __shfl_xor(s, 8);
                att[mf][r] = s + b2v;
            }

        // ---- exp (no max subtraction) + L reduce ----
        float ev[2][4];
        float L = 0.0f;
        #pragma unroll
        for (int mf = 0; mf < 2; ++mf)
            #pragma unroll
            for (int r = 0; r < 4; ++r) {
                ev[mf][r] = __expf(att[mf][r]);
                L += ev[mf][r];
            }
        L += __shfl_xor(L, 16);
        L += __shfl_xor(L, 32);

        if (m16 == 0) {
            #pragma unroll
            for (int mf = 0; mf < 2; ++mf)
                #pragma unroll
                for (int r = 0; r < 4; ++r)
                    ebuf[wv][mf * 16 + quad * 4 + r] = ev[mf][r];
        }
        // same-wave DS ordering; compiler inserts lgkmcnt wait before reads

        // ---- weighted sum: o[d] = sum_n e_n * x[n][d]  (x fp32, L2-hot) ----
        const int G  = lane >> 5;            // n-half (16 each)
        const int db = (lane & 31) * 4;      // d-base (float4)
        f32x4 e4[4];
        #pragma unroll
        for (int i = 0; i < 4; ++i)
            e4[i] = *(const f32x4*)&ebuf[wv][G * 16 + i * 4];

        f32x4 o = {0.0f, 0.0f, 0.0f, 0.0f};
        const float* xr = xb + (size_t)(n0 + G * 16) * NHID + db;
        #pragma unroll
        for (int jj = 0; jj < 16; ++jj) {
            f32x4 xv = *(const f32x4*)(xr + (size_t)jj * NHID);
            o += xv * e4[jj >> 2][jj & 3];
        }
        #pragma unroll
        for (int i = 0; i < 4; ++i) o[i] += __shfl_xor(o[i], 32);

        float* p = part + (size_t)(b * NPART + tile) * PART_STRIDE;
        if (lane == 0) p[0] = L;
        if (lane < 32) *(f32x4*)(p + O_OFF + db) = o;
    }
}

// --------------------------------------------------------------------------
// Kernel C: merge 128 partials per batch -> out[b][d]
// No max pass: S = sum of L_p (block reduce), then a coalesced plain sum
// over partials. No exp, single __syncthreads.
// --------------------------------------------------------------------------
__global__ void finalize(const float* __restrict__ part,
                         float* __restrict__ out) {
    __shared__ float wred[2];

    const int b = blockIdx.x;
    const int d = threadIdx.x;     // 0..127 (= partial index in phase 1)
    const float* pb = part + (size_t)b * NPART * PART_STRIDE;

    // phase 1: S = sum of per-partial L
    float s = pb[(size_t)d * PART_STRIDE];
    s += __shfl_xor(s, 1);
    s += __shfl_xor(s, 2);
    s += __shfl_xor(s, 4);
    s += __shfl_xor(s, 8);
    s += __shfl_xor(s, 16);
    s += __shfl_xor(s, 32);
    if ((d & 63) == 0) wred[d >> 6] = s;
    __syncthreads();
    const float S = wred[0] + wred[1];

    // phase 2: acc over partials, d is the hidden index (coalesced)
    float acc = 0.0f;
    #pragma unroll 8
    for (int p = 0; p < NPART; ++p)
        acc += pb[(size_t)p * PART_STRIDE + O_OFF + d];
    out[b * NHID + d] = acc / S;
}

// --------------------------------------------------------------------------
extern "C" void kernel_launch(void* const* d_in, const int* in_sizes, int n_in,
                              void* d_out, int out_size, void* d_ws, size_t ws_size,
                              hipStream_t stream) {
    const float* inputs = (const float*)d_in[0];
    const int*   index  = (const int*)  d_in[1];
    // d_in[2] = claims (unused by forward)
    const float* W1     = (const float*)d_in[3];
    const float* b1     = (const float*)d_in[4];
    const float* W2     = (const float*)d_in[5];
    const float* b2     = (const float*)d_in[6];
    float* out = (float*)d_out;

    float* part = (float*)d_ws;                 // 128*128*136 floats ~= 8.9 MB

    dim3 gB(NPART / (4 * TPW), BATCH);          // 16 x 128 = 2048 blocks, 4 waves
    att_partial<<<gB, dim3(256), 0, stream>>>(inputs, index, W1, b1, W2, b2, part);

    finalize<<<dim3(BATCH), dim3(NHID), 0, stream>>>(part, out);
}